// Round 4
// baseline (1767.801 us; speedup 1.0000x reference)
//
#include <hip/hip_runtime.h>
#include <math.h>

#define NP 10000
#define KPAD 10048      // NP rounded up to multiple of 64
#define KS 10           // split-K chunks
#define KC 1024         // K per chunk (multiple of 64); last chunk = 832
#define EPSBN 1e-5f

typedef _Float16 h8 __attribute__((ext_vector_type(8)));
typedef _Float16 h4 __attribute__((ext_vector_type(4)));
typedef float f4 __attribute__((ext_vector_type(4)));

__device__ __forceinline__ void gload_lds16(const _Float16* g, _Float16* l) {
    __builtin_amdgcn_global_load_lds(
        (const __attribute__((address_space(1))) unsigned int*)g,
        (__attribute__((address_space(3))) unsigned int*)l,
        16, 0, 0);
}

// ---------------- small kernels (verified R1-R3) -----------------------------

__global__ __launch_bounds__(256) void compute_v_kern(
    const float* __restrict__ La, const float* __restrict__ vap,
    const float* __restrict__ vbp, float* __restrict__ v1, float* __restrict__ v2)
{
    int i = blockIdx.x * 256 + threadIdx.x;
    if (i >= NP) return;
    float la = La[i];
    float va = vap[0], vb = vbp[0];
    v1[i] = powf(la, va);
    float w = 2.0f * (la - 1e-8f) - 1.0f;
    v2[i] = powf(w * w + 1.0f, vb);
}

__global__ __launch_bounds__(256) void dual_linear_kern(
    const float* __restrict__ S, const float* __restrict__ Xin,
    const float* __restrict__ Ww, const float* __restrict__ wb,
    const float* __restrict__ Lw, const float* __restrict__ lb,
    float* __restrict__ h, float* __restrict__ r,
    double* __restrict__ sum1, double* __restrict__ sq1,
    int din, int dl)
{
    __shared__ float Sr[4][128];
    __shared__ float Xr[4][128];
    __shared__ float hsh[4][64];
    const int tid = threadIdx.x;
    const int row0 = blockIdx.x * 4;
    for (int idx = tid; idx < 4 * din; idx += 256) {
        const int rr = idx / din;
        const int k  = idx - rr * din;
        Sr[rr][k] = S  [(size_t)(row0 + rr) * din + k];
        Xr[rr][k] = Xin[(size_t)(row0 + rr) * din + k];
    }
    __syncthreads();
    const int rr = tid >> 6;
    const int c  = tid & 63;
    float acc = wb[c];
    for (int k = 0; k < din; ++k) acc = fmaf(Sr[rr][k], Ww[k * 64 + c], acc);
    h[(size_t)(row0 + rr) * 64 + c] = acc;
    hsh[rr][c] = acc;
    if (c < dl) {
        float a2 = lb[c];
        for (int k = 0; k < din; ++k) a2 = fmaf(Xr[rr][k], Lw[k * dl + c], a2);
        r[(size_t)(row0 + rr) * dl + c] = a2;
    }
    __syncthreads();
    if (tid < 64) {
        float s = hsh[0][tid] + hsh[1][tid] + hsh[2][tid] + hsh[3][tid];
        float q = hsh[0][tid] * hsh[0][tid] + hsh[1][tid] * hsh[1][tid]
                + hsh[2][tid] * hsh[2][tid] + hsh[3][tid] * hsh[3][tid];
        atomicAdd(&sum1[tid], (double)s);
        atomicAdd(&sq1[tid],  (double)q);
    }
}

__global__ void bn_finalize_kern(const double* __restrict__ sum, const double* __restrict__ sq,
                                 float* __restrict__ mean, float* __restrict__ rstd)
{
    const int c = threadIdx.x;
    double m   = sum[c] / (double)NP;
    double var = sq[c] / (double)NP - m * m;
    mean[c] = (float)m;
    rstd[c] = rsqrtf((float)var + EPSBN);
}

__global__ __launch_bounds__(256) void apply1_kern(
    const float* __restrict__ h, const float* __restrict__ r,
    const float* __restrict__ g1, const float* __restrict__ b1,
    const float* __restrict__ mean1, const float* __restrict__ rstd1,
    float* __restrict__ Xn, double* __restrict__ sum2, double* __restrict__ sq2)
{
    __shared__ float sh[256];
    __shared__ float sh2[256];
    const int tid = threadIdx.x;
    const int idx = blockIdx.x * 256 + tid;
    const int c = tid & 63;
    float v = h[idx];
    v = fmaf(g1[c] * (v - mean1[c]), rstd1[c], b1[c]);
    v = fmaxf(v, 0.f);
    float x = fmaxf(v + r[idx], 0.f);
    Xn[idx] = x;
    sh[tid]  = x;
    sh2[tid] = x * x;
    __syncthreads();
    if (tid < 64) {
        float s = sh[tid]  + sh[tid + 64]  + sh[tid + 128]  + sh[tid + 192];
        float q = sh2[tid] + sh2[tid + 64] + sh2[tid + 128] + sh2[tid + 192];
        atomicAdd(&sum2[tid], (double)s);
        atomicAdd(&sq2[tid],  (double)q);
    }
}

__global__ __launch_bounds__(256) void apply2_kern(
    const float* __restrict__ Xn, const float* __restrict__ g2, const float* __restrict__ b2,
    const float* __restrict__ mean2, const float* __restrict__ rstd2, float* __restrict__ Xout)
{
    const int idx = blockIdx.x * 256 + threadIdx.x;
    const int c = idx & 63;
    Xout[idx] = fmaf(g2[c] * (Xn[idx] - mean2[c]), rstd2[c], b2[c]);
}

__global__ __launch_bounds__(64) void final_row_kern(
    const float* __restrict__ h, const float* __restrict__ r40,
    const float* __restrict__ g1, const float* __restrict__ b1,
    const float* __restrict__ mean1, const float* __restrict__ rstd1,
    const float* __restrict__ mlp_w, const float* __restrict__ mlp_b,
    float* __restrict__ out)
{
    __shared__ float hh[64];
    __shared__ float o[40];
    __shared__ float lse;
    const int row = blockIdx.x;
    const int j = threadIdx.x;
    float v = h[(size_t)row * 64 + j];
    v = fmaf(g1[j] * (v - mean1[j]), rstd1[j], b1[j]);
    hh[j] = fmaxf(v, 0.f);
    __syncthreads();
    if (j < 40) {
        float acc = mlp_b[j];
        #pragma unroll
        for (int c2 = 0; c2 < 64; ++c2) acc = fmaf(hh[c2], mlp_w[c2 * 40 + j], acc);
        float s = 1.0f / (1.0f + expf(-acc));
        o[j] = s + r40[(size_t)row * 40 + j];
    }
    __syncthreads();
    if (j == 0) {
        float m = -1e30f;
        for (int t = 0; t < 40; ++t) m = fmaxf(m, o[t]);
        float se = 0.f;
        for (int t = 0; t < 40; ++t) se += expf(o[t] - m);
        lse = m + logf(se);
    }
    __syncthreads();
    if (j < 40) out[(size_t)row * 40 + j] = o[j] - lse;
}

// ---------------- conversion / transpose kernels -----------------------------

__global__ __launch_bounds__(256) void convert_u_kern(
    const float* __restrict__ U, _Float16* __restrict__ U16, _Float16* __restrict__ U16T)
{
    __shared__ float S[64][68];
    const int tid = threadIdx.x;
    const int r0 = blockIdx.x * 64, c0 = blockIdx.y * 64;
    const int r  = tid >> 2;
    const int cq = (tid & 3) * 16;
    const int gr = r0 + r;
    float v[16];
    const bool cvalid = (c0 + cq + 16 <= NP);   // NP % 16 == 0
    if (gr < NP && cvalid) {
        const float* src = U + (size_t)gr * NP + c0 + cq;
        float4 a = *(const float4*)(src);
        float4 b = *(const float4*)(src + 4);
        float4 c = *(const float4*)(src + 8);
        float4 d = *(const float4*)(src + 12);
        v[0]=a.x; v[1]=a.y; v[2]=a.z; v[3]=a.w; v[4]=b.x; v[5]=b.y; v[6]=b.z; v[7]=b.w;
        v[8]=c.x; v[9]=c.y; v[10]=c.z; v[11]=c.w; v[12]=d.x; v[13]=d.y; v[14]=d.z; v[15]=d.w;
    } else {
        #pragma unroll
        for (int j = 0; j < 16; ++j) v[j] = 0.f;
    }
    if (gr < NP) {
        h8 x0, x1;
        #pragma unroll
        for (int j = 0; j < 8; ++j) { x0[j] = (_Float16)v[j]; x1[j] = (_Float16)v[8 + j]; }
        _Float16* dst = U16 + (size_t)gr * KPAD + c0 + cq;
        *(h8*)(dst) = x0;
        *(h8*)(dst + 8) = x1;
    }
    #pragma unroll
    for (int j = 0; j < 16; ++j) S[r][cq + j] = v[j];
    __syncthreads();
    const int oc = c0 + (tid >> 2);
    const int kq = (tid & 3) * 16;
    if (oc < NP) {
        h8 x0, x1;
        #pragma unroll
        for (int j = 0; j < 8; ++j) {
            x0[j] = (_Float16)S[kq + j][tid >> 2];
            x1[j] = (_Float16)S[kq + 8 + j][tid >> 2];
        }
        _Float16* dst = U16T + (size_t)oc * KPAD + r0 + kq;
        *(h8*)(dst) = x0;
        *(h8*)(dst + 8) = x1;
    }
}

__global__ __launch_bounds__(256) void bt_kern(
    const float* __restrict__ src, const float* __restrict__ vs,
    _Float16* __restrict__ Bt, int d)
{
    __shared__ float S[64][68];
    const int tid = threadIdx.x;
    const int k0 = blockIdx.x * 64, n0 = blockIdx.y * 64;
    const int r  = tid >> 2;
    const int cq = (tid & 3) * 16;
    const int gk = k0 + r;
    float v[16];
    if (gk < NP) {
        const float sc = vs ? vs[gk] : 1.0f;
        const float* sp = src + (size_t)gk * d + n0 + cq;
        float4 a = *(const float4*)(sp);
        float4 b = *(const float4*)(sp + 4);
        float4 c = *(const float4*)(sp + 8);
        float4 e = *(const float4*)(sp + 12);
        v[0]=a.x*sc; v[1]=a.y*sc; v[2]=a.z*sc; v[3]=a.w*sc;
        v[4]=b.x*sc; v[5]=b.y*sc; v[6]=b.z*sc; v[7]=b.w*sc;
        v[8]=c.x*sc; v[9]=c.y*sc; v[10]=c.z*sc; v[11]=c.w*sc;
        v[12]=e.x*sc; v[13]=e.y*sc; v[14]=e.z*sc; v[15]=e.w*sc;
    } else {
        #pragma unroll
        for (int j = 0; j < 16; ++j) v[j] = 0.f;
    }
    #pragma unroll
    for (int j = 0; j < 16; ++j) S[r][cq + j] = v[j];
    __syncthreads();
    const int on = n0 + (tid >> 2);
    const int kq = (tid & 3) * 16;
    h8 x0, x1;
    #pragma unroll
    for (int j = 0; j < 8; ++j) {
        x0[j] = (_Float16)S[kq + j][tid >> 2];
        x1[j] = (_Float16)S[kq + 8 + j][tid >> 2];
    }
    _Float16* dst = Bt + (size_t)on * KPAD + k0 + kq;
    *(h8*)(dst) = x0;
    *(h8*)(dst + 8) = x1;
}

// split-K reduce (fp16 partials) + optional scale + transpose to Bt fp16.
__global__ __launch_bounds__(256) void reduce_to_bt(
    const _Float16* __restrict__ P, const float* __restrict__ vs,
    _Float16* __restrict__ Bt, int cnt, int dshift)
{
    const int e4 = (blockIdx.x * 256 + threadIdx.x) * 4;
    if (e4 >= cnt) return;
    h4 p = *(const h4*)(P + e4);
    float a0 = (float)p[0], a1 = (float)p[1], a2 = (float)p[2], a3 = (float)p[3];
    #pragma unroll
    for (int z = 1; z < KS; ++z) {
        h4 q = *(const h4*)(P + (size_t)z * cnt + e4);
        a0 += (float)q[0]; a1 += (float)q[1]; a2 += (float)q[2]; a3 += (float)q[3];
    }
    const int k = e4 >> dshift;
    const int n = e4 & ((1 << dshift) - 1);
    const float s = vs ? vs[k] : 1.0f;
    Bt[(size_t)(n + 0) * KPAD + k] = (_Float16)(a0 * s);
    Bt[(size_t)(n + 1) * KPAD + k] = (_Float16)(a1 * s);
    Bt[(size_t)(n + 2) * KPAD + k] = (_Float16)(a2 * s);
    Bt[(size_t)(n + 3) * KPAD + k] = (_Float16)(a3 * s);
}

// split-K reduce (fp16 partials) -> fp32 row-major output.
__global__ __launch_bounds__(256) void reduce_partials(
    const _Float16* __restrict__ P, float* __restrict__ out, int cnt)
{
    const int e4 = (blockIdx.x * 256 + threadIdx.x) * 4;
    if (e4 >= cnt) return;
    h4 p = *(const h4*)(P + e4);
    float a0 = (float)p[0], a1 = (float)p[1], a2 = (float)p[2], a3 = (float)p[3];
    #pragma unroll
    for (int z = 1; z < KS; ++z) {
        h4 q = *(const h4*)(P + (size_t)z * cnt + e4);
        a0 += (float)q[0]; a1 += (float)q[1]; a2 += (float)q[2]; a3 += (float)q[3];
    }
    float4 o = make_float4(a0, a1, a2, a3);
    *(float4*)(out + e4) = o;
}

// ---------------- MFMA GEMM --------------------------------------------------
// Stage R rows (row-major fp16, stride KPAD) x 64 k-cols into LDS [R][64] via
// global_load_lds dwordx4. Chunk (16B) position p of row r holds chunk p^(r&7).
template<int R>
__device__ __forceinline__ void stage_rows(
    const _Float16* __restrict__ g, _Float16* lds, size_t row0, int k0,
    int wave, int lane)
{
    const int rsub = lane >> 3;          // 0..7
    const int csub = lane & 7;           // chunk position
    const int c    = csub ^ rsub;        // global chunk index
    #pragma unroll
    for (int j = wave; j < R / 8; j += 4) {
        const size_t grow = row0 + (size_t)(j * 8 + rsub);
        gload_lds16(g + grow * KPAD + k0 + c * 8, lds + j * 512);
    }
}

// BM=64, BK=64, BN = 64 or 128. 4 waves: 2x2 over (m,n), WM=32.
template<int BN>
__global__ __launch_bounds__(256) void mfma_gemm(
    const _Float16* __restrict__ A, const _Float16* __restrict__ Bt,
    _Float16* __restrict__ P)
{
    constexpr int WN  = BN / 2;
    constexpr int WTN = BN / 32;
    __shared__ _Float16 As[64 * 64];
    __shared__ _Float16 Bs[BN * 64];

    const int tid  = threadIdx.x;
    const int m0   = blockIdx.x * 64;
    const int z    = blockIdx.z;
    const int k_begin = z * KC;
    const int k_end   = min(KPAD, k_begin + KC);
    const int lane = tid & 63;
    const int wave = tid >> 6;
    const int wm = wave & 1, wn = wave >> 1;
    const int lr = lane & 15, quad = lane >> 4;

    f4 acc[2][WTN];
    #pragma unroll
    for (int i = 0; i < 2; ++i)
        #pragma unroll
        for (int j = 0; j < WTN; ++j) {
            f4 zz = {0.f, 0.f, 0.f, 0.f};
            acc[i][j] = zz;
        }

    for (int k0 = k_begin; k0 < k_end; k0 += 64) {
        stage_rows<64>(A, As, (size_t)m0, k0, wave, lane);
        stage_rows<BN>(Bt, Bs, 0, k0, wave, lane);
        __syncthreads();
        #pragma unroll
        for (int g = 0; g < 2; ++g) {
            h8 af[2];
            h8 bf[WTN];
            #pragma unroll
            for (int i = 0; i < 2; ++i) {
                const int row = wm * 32 + i * 16 + lr;
                af[i] = *(const h8*)(As + row * 64 + ((((g << 2) | quad) ^ (row & 7)) << 3));
            }
            #pragma unroll
            for (int j = 0; j < WTN; ++j) {
                const int row = wn * WN + j * 16 + lr;
                bf[j] = *(const h8*)(Bs + row * 64 + ((((g << 2) | quad) ^ (row & 7)) << 3));
            }
            #pragma unroll
            for (int i = 0; i < 2; ++i)
                #pragma unroll
                for (int j = 0; j < WTN; ++j)
                    acc[i][j] = __builtin_amdgcn_mfma_f32_16x16x32_f16(af[i], bf[j], acc[i][j], 0, 0, 0);
        }
        __syncthreads();
    }

    _Float16* __restrict__ Cp = P + (size_t)z * (size_t)NP * (size_t)BN;
    #pragma unroll
    for (int i = 0; i < 2; ++i) {
        const int mb = m0 + wm * 32 + i * 16 + quad * 4;
        #pragma unroll
        for (int j = 0; j < WTN; ++j) {
            const int n = wn * WN + j * 16 + lr;
            #pragma unroll
            for (int r = 0; r < 4; ++r) {
                const int m = mb + r;
                if (m < NP) Cp[(size_t)m * BN + n] = (_Float16)acc[i][j][r];
            }
        }
    }
}

// -----------------------------------------------------------------------------

extern "C" void kernel_launch(void* const* d_in, const int* in_sizes, int n_in,
                              void* d_out, int out_size, void* d_ws, size_t ws_size,
                              hipStream_t stream)
{
    const float* X     = (const float*)d_in[0];
    const float* La    = (const float*)d_in[1];
    const float* U     = (const float*)d_in[2];
    const float* mlp_w = (const float*)d_in[31];
    const float* mlp_b = (const float*)d_in[32];

    char* ws = (char*)d_ws;
    size_t off = 0;
    auto alloc = [&](size_t bytes) -> void* {
        void* p = ws + off;
        off = (off + bytes + 255) & ~(size_t)255;
        return p;
    };

    _Float16* U16  = (_Float16*)alloc((size_t)10112 * KPAD * 2);
    _Float16* U16T = (_Float16*)alloc((size_t)10112 * KPAD * 2);
    _Float16* Bt   = (_Float16*)alloc((size_t)128 * KPAD * 2);
    _Float16* P    = (_Float16*)alloc((size_t)KS * NP * 128 * 2);
    float*  bufB  = (float*)alloc((size_t)NP * 128 * 4);
    float*  h     = (float*)alloc((size_t)NP * 64 * 4);
    float*  r     = (float*)alloc((size_t)NP * 64 * 4);
    float*  Xn    = (float*)alloc((size_t)NP * 64 * 4);
    float*  Xbuf  = (float*)alloc((size_t)NP * 64 * 4);
    float*  v1    = (float*)alloc((size_t)NP * 4);
    float*  v2    = (float*)alloc((size_t)NP * 4);
    double* stats = (double*)alloc((size_t)3 * 256 * 8);
    float*  mr    = (float*)alloc((size_t)3 * 256 * 4);

    hipMemsetAsync(stats, 0, 3 * 256 * 8, stream);

    convert_u_kern<<<dim3(157, 157), 256, 0, stream>>>(U, U16, U16T);

    const float* Xcur = X;
    int din = 128;
    for (int i = 0; i < 3; ++i) {
        const int base = 3 + i * 10;
        const float* vap = (const float*)d_in[base + 0];
        const float* vbp = (const float*)d_in[base + 1];
        const float* Ww  = (const float*)d_in[base + 2];
        const float* wb  = (const float*)d_in[base + 3];
        const float* g1  = (const float*)d_in[base + 4];
        const float* b1  = (const float*)d_in[base + 5];
        const float* Lw  = (const float*)d_in[base + 6];
        const float* lb  = (const float*)d_in[base + 7];

        compute_v_kern<<<(NP + 255) / 256, 256, 0, stream>>>(La, vap, vbp, v1, v2);

        const int cnt    = NP * din;
        const int dshift = (din == 128) ? 7 : 6;
        const int rb     = cnt / 1024;          // exact: 1250 / 625
        dim3 gg(157, 1, KS);

        // t1 = U^T@X ; t2 = U@(v1*t1) ; t3 = U^T@t2 ; s = U@(v2*t3)
        bt_kern<<<dim3(157, din / 64), 256, 0, stream>>>(Xcur, nullptr, Bt, din);
        if (din == 128) {
            mfma_gemm<128><<<gg, 256, 0, stream>>>(U16T, Bt, P);
            reduce_to_bt<<<rb, 256, 0, stream>>>(P, v1, Bt, cnt, dshift);
            mfma_gemm<128><<<gg, 256, 0, stream>>>(U16, Bt, P);
            reduce_to_bt<<<rb, 256, 0, stream>>>(P, nullptr, Bt, cnt, dshift);
            mfma_gemm<128><<<gg, 256, 0, stream>>>(U16T, Bt, P);
            reduce_to_bt<<<rb, 256, 0, stream>>>(P, v2, Bt, cnt, dshift);
            mfma_gemm<128><<<gg, 256, 0, stream>>>(U16, Bt, P);
            reduce_partials<<<rb, 256, 0, stream>>>(P, bufB, cnt);
        } else {
            mfma_gemm<64><<<gg, 256, 0, stream>>>(U16T, Bt, P);
            reduce_to_bt<<<rb, 256, 0, stream>>>(P, v1, Bt, cnt, dshift);
            mfma_gemm<64><<<gg, 256, 0, stream>>>(U16, Bt, P);
            reduce_to_bt<<<rb, 256, 0, stream>>>(P, nullptr, Bt, cnt, dshift);
            mfma_gemm<64><<<gg, 256, 0, stream>>>(U16T, Bt, P);
            reduce_to_bt<<<rb, 256, 0, stream>>>(P, v2, Bt, cnt, dshift);
            mfma_gemm<64><<<gg, 256, 0, stream>>>(U16, Bt, P);
            reduce_partials<<<rb, 256, 0, stream>>>(P, bufB, cnt);
        }

        const int dl = (i < 2) ? 64 : 40;
        double* sum1 = stats + i * 256;
        double* sq1  = sum1 + 64;
        double* sum2 = sum1 + 128;
        double* sq2  = sum1 + 192;
        float* mean1 = mr + i * 256;
        float* rstd1 = mean1 + 64;
        float* mean2 = mean1 + 128;
        float* rstd2 = mean1 + 192;

        dual_linear_kern<<<NP / 4, 256, 0, stream>>>(bufB, Xcur, Ww, wb, Lw, lb,
                                                     h, r, sum1, sq1, din, dl);
        bn_finalize_kern<<<1, 64, 0, stream>>>(sum1, sq1, mean1, rstd1);
        if (i < 2) {
            const float* g2 = (const float*)d_in[base + 8];
            const float* b2 = (const float*)d_in[base + 9];
            apply1_kern<<<NP / 4, 256, 0, stream>>>(h, r, g1, b1, mean1, rstd1, Xn, sum2, sq2);
            bn_finalize_kern<<<1, 64, 0, stream>>>(sum2, sq2, mean2, rstd2);
            apply2_kern<<<NP / 4, 256, 0, stream>>>(Xn, g2, b2, mean2, rstd2, Xbuf);
            Xcur = Xbuf;
            din = 64;
        } else {
            final_row_kern<<<NP, 64, 0, stream>>>(h, r, g1, b1, mean1, rstd1,
                                                  mlp_w, mlp_b, (float*)d_out);
        }
    }
}